// Round 6
// baseline (174.501 us; speedup 1.0000x reference)
//
#include <hip/hip_runtime.h>

// (B,P,C,H,W)=(256,10,32,8,8); Tm=19, Ta=10, hw=64. All I/O fp32.
// Horner: A_0=[F_0;1]; A_{p+1}=A_p*M_p+[F_{p+1};1] (p=0..8) -> A_9=[G;W]
// out[b,t,c,j] = (G[c,:].M_t[:,j]) / (W.M_t[:,j] + eps)
//
// v16 (from v12, the measured-best structure; v13/v14/v15 all regressed):
// phase-1 issue-count cut. Old inner loop: ds_read_b32 + 2 v_readlane +
// 2 fmac per k (320 instr/step/wave). New: A-row state mirrored in LDS
// (wave-private rows, no barrier), M^T staged as McT[kb][j][4] so one
// conflict-free ds_read_b128 yields m for k=4kb..4kb+3 (banks tile as
// 4j+q) and one broadcast ds_read_b128 yields A[4kb..4kb+3]. 16 x
// (3 b128 + 8 fmac) = 176 instr/step (-45%). FMA order k-ascending,
// bit-identical to v12. Phase 2 verbatim v12 (plain-loop form).
// Staging: 8 coalesced b32 global loads + 2 b128 ds_writes per wave/step.
// LDS: 32KB McT dbuf + 4.25KB Ar + 5KB Gt = 41.25KB -> 2 blocks/CU.

#define EPSV 1e-6f

__global__ __launch_bounds__(512, 2) void k_fused(
    const float* __restrict__ feats,   // (256,10,32,64)
    const float* __restrict__ sim,     // (256,19,64,64)
    float* __restrict__ out)           // (2560,32,64)
{
    // McT[buf][kb*256 + j*4 + q] = M[4kb+q][j]  (16KB per buf, b128-clean)
    __shared__ __attribute__((aligned(16))) float McT[2][4096];
    __shared__ __attribute__((aligned(16))) float Ar[1088];   // rows 0..15 G-half, 16 = W
    __shared__ __attribute__((aligned(16))) float Gt[1280];   // phase-2 handoff

    const int tid  = threadIdx.x;
    const int lane = tid & 63;
    const int wave = tid >> 6;          // 0..7
    const int b    = blockIdx.x & 255;  // pair (b, b+256) -> same XCD
    const int h    = blockIdx.x >> 8;   // row-half of the batch

    const float* fb = feats + (size_t)b * 20480;   // 10*32*64
    const float* sb = sim   + (size_t)b * 77824;   // 19*64*64

    // ---- stage M_0^T: wave w covers kb = 2w, 2w+1 ----
    #pragma unroll
    for (int i = 0; i < 2; ++i) {
        const int kb = 2 * wave + i;
        float4 v;
        v.x = sb[(4 * kb + 0) * 64 + lane];   // coalesced 256B per q
        v.y = sb[(4 * kb + 1) * 64 + lane];
        v.z = sb[(4 * kb + 2) * 64 + lane];
        v.w = sb[(4 * kb + 3) * 64 + lane];
        *(float4*)&McT[0][kb * 256 + lane * 4] = v;
    }

    // ---- A_0 in registers + LDS mirror ----
    const int r0 = 16 * h + 2 * wave;
    float a0 = fb[(r0 + 0) * 64 + lane];
    float a1 = fb[(r0 + 1) * 64 + lane];
    float aw = 1.0f;
    const int ar0 = (2 * wave + 0) * 64;
    const int ar1 = (2 * wave + 1) * 64;
    Ar[ar0 + lane] = a0;
    Ar[ar1 + lane] = a1;
    if (wave == 7) Ar[1024 + lane] = aw;

    __syncthreads();                    // M_0^T + A_0 visible

    for (int p = 0; p < 9; ++p) {
        // global loads for M_{p+1}^T staging: in flight across the k-loop
        float4 st0, st1;
        if (p < 8) {
            const float* __restrict__ Mn = sb + (p + 1) * 4096;
            const int kb0 = 2 * wave, kb1 = 2 * wave + 1;
            st0.x = Mn[(4 * kb0 + 0) * 64 + lane];
            st0.y = Mn[(4 * kb0 + 1) * 64 + lane];
            st0.z = Mn[(4 * kb0 + 2) * 64 + lane];
            st0.w = Mn[(4 * kb0 + 3) * 64 + lane];
            st1.x = Mn[(4 * kb1 + 0) * 64 + lane];
            st1.y = Mn[(4 * kb1 + 1) * 64 + lane];
            st1.z = Mn[(4 * kb1 + 2) * 64 + lane];
            st1.w = Mn[(4 * kb1 + 3) * 64 + lane];
        }
        const float* __restrict__ F = fb + (p + 1) * 2048;
        const float f0 = F[(r0 + 0) * 64 + lane];
        const float f1 = F[(r0 + 1) * 64 + lane];
        const float* __restrict__ Mc = McT[p & 1];

        float c0 = 0.f, c1 = 0.f, cw = 0.f;
        if (wave == 7) {                // wave-uniform branch (rows 14,15 + W)
            #pragma unroll
            for (int kb = 0; kb < 16; ++kb) {
                const float4 m  = *(const float4*)&Mc[kb * 256 + lane * 4];
                const float4 q0 = *(const float4*)&Ar[ar0 + 4 * kb];   // broadcast
                const float4 q1 = *(const float4*)&Ar[ar1 + 4 * kb];
                const float4 qw = *(const float4*)&Ar[1024 + 4 * kb];
                c0 += q0.x * m.x; c0 += q0.y * m.y; c0 += q0.z * m.z; c0 += q0.w * m.w;
                c1 += q1.x * m.x; c1 += q1.y * m.y; c1 += q1.z * m.z; c1 += q1.w * m.w;
                cw += qw.x * m.x; cw += qw.y * m.y; cw += qw.z * m.z; cw += qw.w * m.w;
            }
        } else {
            #pragma unroll
            for (int kb = 0; kb < 16; ++kb) {
                const float4 m  = *(const float4*)&Mc[kb * 256 + lane * 4];
                const float4 q0 = *(const float4*)&Ar[ar0 + 4 * kb];
                const float4 q1 = *(const float4*)&Ar[ar1 + 4 * kb];
                c0 += q0.x * m.x; c0 += q0.y * m.y; c0 += q0.z * m.z; c0 += q0.w * m.w;
                c1 += q1.x * m.x; c1 += q1.y * m.y; c1 += q1.z * m.z; c1 += q1.w * m.w;
            }
        }
        a0 = c0 + f0; a1 = c1 + f1; aw = cw + 1.0f;

        // refresh own Ar rows (wave-private: own reads above are ordered
        // before these writes by lgkmcnt; no other wave touches them)
        Ar[ar0 + lane] = a0;
        Ar[ar1 + lane] = a1;
        if (wave == 7) Ar[1024 + lane] = aw;

        if (p < 8) {
            float* Mw = McT[(p + 1) & 1];      // other buffer: no reader-wait
            *(float4*)&Mw[(2 * wave + 0) * 256 + lane * 4] = st0;
            *(float4*)&Mw[(2 * wave + 1) * 256 + lane * 4] = st1;
            __syncthreads();
        }
    }

    // ---- handoff: half G + W -> Gt (k = lane, transposed writes) ----
    Gt[lane * 20 + 2 * wave + 0] = a0;
    Gt[lane * 20 + 2 * wave + 1] = a1;
    if (wave == 7) Gt[lane * 20 + 16] = aw;
    __syncthreads();

    // ---- phase 2a: job t=wave, 16 rows x 64 cols on the owned half ----
    const int rr = (lane >> 4) * 4;     // 0,4,8,12 (within the half)
    const int jj = (lane & 15) * 4;
    {
        const int t = wave;
        const float* __restrict__ Mt = sb + (9 + t) * 4096;

        float acc[16];
        #pragma unroll
        for (int i = 0; i < 16; ++i) acc[i] = 0.f;
        float wv0 = 0.f, wv1 = 0.f, wv2 = 0.f, wv3 = 0.f;

        #pragma unroll 16
        for (int k = 0; k < 64; ++k) {
            const float4 g  = *(const float4*)&Gt[k * 20 + rr];   // 4 rows @ k
            const float  wk = Gt[k * 20 + 16];                    // W[k]
            const float4 m  = *(const float4*)&Mt[k * 64 + jj];   // global b128
            wv0 += wk * m.x; wv1 += wk * m.y; wv2 += wk * m.z; wv3 += wk * m.w;
            acc[0]  += g.x*m.x; acc[1]  += g.x*m.y; acc[2]  += g.x*m.z; acc[3]  += g.x*m.w;
            acc[4]  += g.y*m.x; acc[5]  += g.y*m.y; acc[6]  += g.y*m.z; acc[7]  += g.y*m.w;
            acc[8]  += g.z*m.x; acc[9]  += g.z*m.y; acc[10] += g.z*m.z; acc[11] += g.z*m.w;
            acc[12] += g.w*m.x; acc[13] += g.w*m.y; acc[14] += g.w*m.z; acc[15] += g.w*m.w;
        }

        float4 rw;
        rw.x = 1.f / (wv0 + EPSV); rw.y = 1.f / (wv1 + EPSV);
        rw.z = 1.f / (wv2 + EPSV); rw.w = 1.f / (wv3 + EPSV);

        float* ob = out + ((size_t)b * 10 + t) * 2048;
        #pragma unroll
        for (int i = 0; i < 4; ++i) {
            float4 o;
            o.x = acc[i * 4 + 0] * rw.x;
            o.y = acc[i * 4 + 1] * rw.y;
            o.z = acc[i * 4 + 2] * rw.z;
            o.w = acc[i * 4 + 3] * rw.w;
            *(float4*)&ob[(16 * h + rr + i) * 64 + jj] = o;
        }
    }

    // ---- phase 2b: t=8,9 split into 8 quarter-jobs (4 rows x 64 cols) ----
    {
        const int t   = 8 + (wave >> 2);               // waves 0-3 -> 8, 4-7 -> 9
        const int row = (wave & 3) * 4 + (lane >> 4);  // 0..15 within the half
        const float* __restrict__ Mt = sb + (9 + t) * 4096;

        float ac0 = 0.f, ac1 = 0.f, ac2 = 0.f, ac3 = 0.f;
        float wv0 = 0.f, wv1 = 0.f, wv2 = 0.f, wv3 = 0.f;

        #pragma unroll 16
        for (int k = 0; k < 64; ++k) {
            const float  g  = Gt[k * 20 + row];        // 16-lane broadcast
            const float  wk = Gt[k * 20 + 16];
            const float4 m  = *(const float4*)&Mt[k * 64 + jj];
            ac0 += g * m.x;  ac1 += g * m.y;  ac2 += g * m.z;  ac3 += g * m.w;
            wv0 += wk * m.x; wv1 += wk * m.y; wv2 += wk * m.z; wv3 += wk * m.w;
        }

        float4 o;
        o.x = ac0 * (1.f / (wv0 + EPSV));
        o.y = ac1 * (1.f / (wv1 + EPSV));
        o.z = ac2 * (1.f / (wv2 + EPSV));
        o.w = ac3 * (1.f / (wv3 + EPSV));

        float* ob = out + ((size_t)b * 10 + t) * 2048;
        *(float4*)&ob[(16 * h + row) * 64 + jj] = o;
    }
}

extern "C" void kernel_launch(void* const* d_in, const int* in_sizes, int n_in,
                              void* d_out, int out_size, void* d_ws, size_t ws_size,
                              hipStream_t stream) {
    const float* feats = (const float*)d_in[0];
    const float* sim   = (const float*)d_in[1];
    k_fused<<<512, 512, 0, stream>>>(feats, sim, (float*)d_out);
}

// Round 7
// 151.945 us; speedup vs baseline: 1.1484x; 1.1484x over previous
//
#include <hip/hip_runtime.h>

// (B,P,C,H,W)=(256,10,32,8,8); Tm=19, Ta=10, hw=64. All I/O fp32.
// Horner: A_0=[F_0;1]; A_{p+1}=A_p*M_p+[F_{p+1};1] (p=0..8) -> A_9=[G;W]
// out[b,t,c,j] = (G[c,:].M_t[:,j]) / (W.M_t[:,j] + eps)
//
// v17: MFMA rewrite. v12-v16 showed the fp32-VALU formulation is pinned at
// ~60-78us (VALU/LDS/latency co-bound). Recast both phases as bf16 MFMA
// (16x16x32) with EXACT 3-way bf16 splits (RNE cvt_pk) and all 9 cross
// products accumulated in fp32 -> fp32-grade numerics. The A/B k-slot
// mapping uncertainty cancels because A and B use the SAME k<->slot
// bijection (any HW permutation gives the same dot product).
//  - grid 512: b=bid&255, h=bid>>8 (t-half). Siblings co-XCD -> shared
//    L2 for the M stream. Phase 1 duplicated (cheap), phase 2 split.
//  - 256 thr = 4 waves = 4 n-tiles of 16 cols. Rows padded 33->48 (3 row
//    tiles); W row = A-row 32 with F==1; rows 33-47 stay zero.
//  - 14-step ring: s=0..8 recursion (M_s), s=9..13 output (M_{s+5h}).
//    M staged by global_load_lds into Mb[2] (16KB each), 1 barrier/step.
//  - A-state transposed in LDS At[2], stride 49 (frag reads conflict-free,
//    writeback odd-stride). G-frags built once, held in regs for 5 t-steps.

#define EPSV 1e-6f

typedef short  bf16x8 __attribute__((ext_vector_type(8)));
typedef float  f32x4  __attribute__((ext_vector_type(4)));
typedef unsigned int uintx4 __attribute__((ext_vector_type(4)));

#define GLOAD_LDS(G, L)                                                       \
    __builtin_amdgcn_global_load_lds(                                         \
        (const __attribute__((address_space(1))) void*)(G),                   \
        (__attribute__((address_space(3))) void*)(L), 16, 0, 0)

// stage one 16KB matrix (4096 floats) into Mb[BUF]; linear both sides.
#define STAGE(MIDX, BUF)                                                      \
    {                                                                         \
        const float* _s = sb + (size_t)(MIDX) * 4096;                         \
        GLOAD_LDS(_s + tid * 4,        &Mb[BUF][tid * 4]);                    \
        GLOAD_LDS(_s + 1024 + tid * 4, &Mb[BUF][1024 + tid * 4]);             \
        GLOAD_LDS(_s + 2048 + tid * 4, &Mb[BUF][2048 + tid * 4]);             \
        GLOAD_LDS(_s + 3072 + tid * 4, &Mb[BUF][3072 + tid * 4]);             \
    }

__device__ __forceinline__ unsigned cvtpk(float a, float b) {
    unsigned r;
    asm("v_cvt_pk_bf16_f32 %0, %1, %2" : "=v"(r) : "v"(a), "v"(b));
    return r;
}

// exact 3-way split of 8 fp32 -> three bf16x8 fragments (non-overlapping)
__device__ __forceinline__ void split8(const float* x,
                                       bf16x8& f1, bf16x8& f2, bf16x8& f3) {
    uintx4 w1, w2, w3;
    #pragma unroll
    for (int p = 0; p < 4; ++p) {
        const float x0 = x[2 * p], x1 = x[2 * p + 1];
        const unsigned a = cvtpk(x0, x1);
        const float y0 = x0 - __uint_as_float(a << 16);
        const float y1 = x1 - __uint_as_float(a & 0xffff0000u);
        const unsigned bq = cvtpk(y0, y1);
        const float z0 = y0 - __uint_as_float(bq << 16);
        const float z1 = y1 - __uint_as_float(bq & 0xffff0000u);
        w1[p] = a; w2[p] = bq; w3[p] = cvtpk(z0, z1);
    }
    f1 = __builtin_bit_cast(bf16x8, w1);
    f2 = __builtin_bit_cast(bf16x8, w2);
    f3 = __builtin_bit_cast(bf16x8, w3);
}

#define MFMA __builtin_amdgcn_mfma_f32_16x16x32_bf16

// C += (A1+A2+A3)*(B1+B2+B3), all 9 products (exact multiply, fp32 accum)
__device__ __forceinline__ f32x4 mm9(f32x4 c,
        bf16x8 a1, bf16x8 a2, bf16x8 a3,
        bf16x8 b1, bf16x8 b2, bf16x8 b3) {
    c = MFMA(a1, b1, c, 0, 0, 0);
    c = MFMA(a1, b2, c, 0, 0, 0);
    c = MFMA(a2, b1, c, 0, 0, 0);
    c = MFMA(a1, b3, c, 0, 0, 0);
    c = MFMA(a2, b2, c, 0, 0, 0);
    c = MFMA(a3, b1, c, 0, 0, 0);
    c = MFMA(a2, b3, c, 0, 0, 0);
    c = MFMA(a3, b2, c, 0, 0, 0);
    c = MFMA(a3, b3, c, 0, 0, 0);
    return c;
}

__global__ __launch_bounds__(256, 2) void k_fused(
    const float* __restrict__ feats,   // (256,10,32,64)
    const float* __restrict__ sim,     // (256,19,64,64)
    float* __restrict__ out)           // (2560,32,64)
{
    __shared__ __attribute__((aligned(16))) float Mb[2][4096];   // 32KB ring
    __shared__ __attribute__((aligned(16))) float At[2][3136];   // 2x 64x49

    const int tid  = threadIdx.x;
    const int lane = tid & 63;
    const int wave = tid >> 6;          // 0..3 = n-tile
    const int lg   = lane >> 4;         // k-subgroup / D-row group
    const int c    = lane & 15;         // A-row / D-col within tile
    const int cb   = 16 * wave + c;     // absolute column
    const int b    = blockIdx.x & 255;  // batch (siblings co-XCD)
    const int h    = blockIdx.x >> 8;   // t-half: t = 5h..5h+4

    const float* fb = feats + (size_t)b * 20480;   // 10*32*64
    const float* sb = sim   + (size_t)b * 77824;   // 19*64*64

    // ---- prologue: At[0] = [F_0; 1; 0-pad] transposed; stage M_0 ----
    {
        const int kk = tid & 63;
        const int r0 = 12 * wave;       // 4 groups x 12 rows = 48
        #pragma unroll
        for (int ii = 0; ii < 12; ++ii) {
            const int r = r0 + ii;
            float v = 0.f;
            if (r < 32)      v = fb[r * 64 + kk];
            else if (r == 32) v = 1.0f;
            At[0][kk * 49 + r] = v;
        }
    }
    STAGE(0, 0);
    __syncthreads();

    // ---- recursion: s=0..8, A_{s+1} = A_s*M_s + [F_{s+1};1;0] ----
    for (int s = 0; s < 9; ++s) {
        if (s < 8) STAGE(s + 1, (s + 1) & 1)
        else       STAGE(9 + 5 * h, 1);            // first output matrix

        const float* __restrict__ F = fb + (s + 1) * 2048;
        f32x4 c0, c1, c2;
        #pragma unroll
        for (int i = 0; i < 4; ++i) {
            c0[i] = F[(4 * lg + i) * 64 + cb];       // rows 0-15
            c1[i] = F[(16 + 4 * lg + i) * 64 + cb];  // rows 16-31
            c2[i] = 0.f;                             // rows 32-47
        }
        if (lg == 0) c2[0] = 1.0f;                   // W row: F == 1

        const float* __restrict__ Mc  = Mb[s & 1];
        const float* __restrict__ Atc = At[s & 1];

        #pragma unroll
        for (int kh = 0; kh < 2; ++kh) {
            float xb[8];
            #pragma unroll
            for (int j = 0; j < 8; ++j)
                xb[j] = Mc[(32 * kh + 8 * lg + j) * 64 + cb];
            bf16x8 b1, b2, b3; split8(xb, b1, b2, b3);

            float xa[8];
            bf16x8 a1, a2, a3;
            #pragma unroll
            for (int j = 0; j < 8; ++j)
                xa[j] = Atc[(32 * kh + 8 * lg + j) * 49 + c];
            split8(xa, a1, a2, a3);
            c0 = mm9(c0, a1, a2, a3, b1, b2, b3);
            #pragma unroll
            for (int j = 0; j < 8; ++j)
                xa[j] = Atc[(32 * kh + 8 * lg + j) * 49 + 16 + c];
            split8(xa, a1, a2, a3);
            c1 = mm9(c1, a1, a2, a3, b1, b2, b3);
            #pragma unroll
            for (int j = 0; j < 8; ++j)
                xa[j] = Atc[(32 * kh + 8 * lg + j) * 49 + 32 + c];
            split8(xa, a1, a2, a3);
            c2 = mm9(c2, a1, a2, a3, b1, b2, b3);
        }

        // writeback A_{s+1} transposed into the other buffer
        float* __restrict__ Atn = At[(s + 1) & 1];
        #pragma unroll
        for (int i = 0; i < 4; ++i) {
            Atn[cb * 49 +      4 * lg + i] = c0[i];
            Atn[cb * 49 + 16 + 4 * lg + i] = c1[i];
            Atn[cb * 49 + 32 + 4 * lg + i] = c2[i];
        }
        __syncthreads();
    }

    // ---- build G fragments once (A_9 lives in At[1]) ----
    bf16x8 g1[6], g2[6], g3[6];        // idx = kh*3 + rt, all static
    #pragma unroll
    for (int kh = 0; kh < 2; ++kh)
        #pragma unroll
        for (int rt = 0; rt < 3; ++rt) {
            float xa[8];
            #pragma unroll
            for (int j = 0; j < 8; ++j)
                xa[j] = At[1][(32 * kh + 8 * lg + j) * 49 + 16 * rt + c];
            split8(xa, g1[kh * 3 + rt], g2[kh * 3 + rt], g3[kh * 3 + rt]);
        }

    // ---- output: s=9..13 -> t = (s-9)+5h, D = [G;W]*M_t, normalize ----
    for (int s = 9; s < 14; ++s) {
        if (s < 13) STAGE(s + 1 + 5 * h, (s + 1) & 1);

        f32x4 c0 = {0.f, 0.f, 0.f, 0.f};
        f32x4 c1 = c0, c2 = c0;
        const float* __restrict__ Mc = Mb[s & 1];

        #pragma unroll
        for (int kh = 0; kh < 2; ++kh) {
            float xb[8];
            #pragma unroll
            for (int j = 0; j < 8; ++j)
                xb[j] = Mc[(32 * kh + 8 * lg + j) * 64 + cb];
            bf16x8 b1, b2, b3; split8(xb, b1, b2, b3);
            c0 = mm9(c0, g1[kh*3+0], g2[kh*3+0], g3[kh*3+0], b1, b2, b3);
            c1 = mm9(c1, g1[kh*3+1], g2[kh*3+1], g3[kh*3+1], b1, b2, b3);
            c2 = mm9(c2, g1[kh*3+2], g2[kh*3+2], g3[kh*3+2], b1, b2, b3);
        }

        // W.M_t sits in c2[0] of lane-group 0 (row 32); broadcast per column
        const float wv = __shfl(c2[0], lane & 15);
        const float rw = 1.f / (wv + EPSV);

        float* ob = out + ((size_t)b * 10 + (s - 9) + 5 * h) * 2048;
        #pragma unroll
        for (int i = 0; i < 4; ++i) {
            ob[(     4 * lg + i) * 64 + cb] = c0[i] * rw;
            ob[(16 + 4 * lg + i) * 64 + cb] = c1[i] * rw;
        }
        if (s < 13) __syncthreads();
    }
}

extern "C" void kernel_launch(void* const* d_in, const int* in_sizes, int n_in,
                              void* d_out, int out_size, void* d_ws, size_t ws_size,
                              hipStream_t stream) {
    const float* feats = (const float*)d_in[0];
    const float* sim   = (const float*)d_in[1];
    k_fused<<<512, 256, 0, stream>>>(feats, sim, (float*)d_out);
}